// Round 7
// baseline (141.509 us; speedup 1.0000x reference)
//
#include <hip/hip_runtime.h>
#include <hip/hip_bf16.h>

// QuantisedMonDEQ: n=512, d=784, B=128, C=10. All inputs/outputs float32.
// z_{t+1} = relu(0.5 z + 0.5 (Wq z + Ux)), 40 iters; logits = z*^T Wc^T + bc.
//
// INT8 formulation: Wq = sW*Q, Q = rint(W/sW) exact int8. z held as Q4.11
// fixed point v (int16), split v = 256*zh + (zlm+128), zh,zlm int8.
//   Q.v = 256*(Q.zh) + Q.zlm + 128*rowsum(Q)   (rowsum folded into Ux).
// Iters 1..27: hi-plane only; iters 28..39 both planes. Z (=2048*z, exact
// 2^11 scaling) + Ux fold live in registers; LDS carries only the int8
// B-plane transpose. Rowsum via ones-vector i8 MFMA. Pack: cvt_pk_i16 + perm.
//
// Round-7 (post-mortem r6): overhead is ~50us FIXED (not per-node) ->
// attack kernel time. Solve is LDS-bound (128-256 b128/CU/iter ~2300cyc +
// 758 conflict-cyc/iter, lockstep waves reading identical fragment
// sequence). Changes:
//  * kc-STAGGER: wave w consumes kc in order (j+w)&7 -- A-frags loaded
//    pre-rotated so register indices stay static (rule #20); i32 accum is
//    commutative -> bit-exact.
//  * UxT producers re-tiled: 16 blocks x 32 U-rows, wave=(rowhalf,cgroup),
//    all 16 waves active; per-output kc order unchanged -> bit-exact.
//  * split counters cntW/cntU: solve overlaps A-load+rowsum+Wc->LDS staging
//    under the UxT tail; logits read Wc from LDS (broadcast, was 80 scalar
//    global loads/lane).
// Dispatch: scales(193) -> fused(88): 0..63 W-quant | 64..79 UxT | 80..87 solve.

#define N_DIM 512
#define D_DIM 784
#define B_DIM 128
#define C_DIM 10
#define QMAX 127.0f
#define N_ITERS 40
#define HILO_START 28
#define ZPITCH 528     // bytes per column plane row; 16B-aligned
#define MT 2           // 16-row M-tiles per wave (16 waves x 32 rows = 512)
#define XPITCH 800     // bf16 elems per x row in ws (784 data + 16 zero pad)
#define QUPITCH 808    // bf16 elems per U row in LDS (pad spreads banks)

typedef int    i32x4  __attribute__((ext_vector_type(4)));
typedef float  f32x4  __attribute__((ext_vector_type(4)));
typedef __bf16 bf16x8 __attribute__((ext_vector_type(8)));
typedef short  s16x2  __attribute__((ext_vector_type(2)));

// ws float offsets (scalars/partials fully rewritten each replay)
#define WSF_PW   0                   // 64 W partial maxes
#define WSF_PU   64                  // 64 U partial maxes
#define WSF_SB   128                 // sb scalar
#define WSF_CNTW 160                 // int: W-quant done counter (own line)
#define WSF_CNTU 224                 // int: UxT done counter (own line)
#define WSF_BQ   288                 // bq[512] fp32
#define WSF_XH   800                 // xh bf16 [128][XPITCH] = 51200 floats
#define WSF_XL   (WSF_XH + 51200)    // xl bf16 [128][XPITCH]
#define WSF_QP8  (WSF_XL + 51200)    // Qp8 int8 512x512 = 65536 floats
#define WSF_UXT  (WSF_QP8 + 65536)   // UxT fp32 [128][512]

#define N_PW 64
#define N_PU 16

__device__ __forceinline__ float pscale64(const float* __restrict__ p) {
    float m = 0.0f;
#pragma unroll 16
    for (int i = 0; i < 64; ++i) m = fmaxf(m, p[i]);
    return m * (1.0f / QMAX);
}

// vq[0..3] (>=0) -> saturate to i16, h = hi bytes, l = lo bytes ^ 0x80.
__device__ __forceinline__ void pack_hl(const int vq[4], unsigned int& h, unsigned int& l) {
    int pk01, pk23;
#if __has_builtin(__builtin_amdgcn_cvt_pk_i16)
    union { s16x2 v; int i; } u0, u1;
    u0.v = __builtin_amdgcn_cvt_pk_i16(vq[0], vq[1]);
    u1.v = __builtin_amdgcn_cvt_pk_i16(vq[2], vq[3]);
    pk01 = u0.i; pk23 = u1.i;
#else
    asm("v_cvt_pk_i16_i32 %0, %1, %2" : "=v"(pk01) : "v"(vq[0]), "v"(vq[1]));
    asm("v_cvt_pk_i16_i32 %0, %1, %2" : "=v"(pk23) : "v"(vq[2]), "v"(vq[3]));
#endif
    h = __builtin_amdgcn_perm((unsigned int)pk23, (unsigned int)pk01, 0x07050301u);
    l = __builtin_amdgcn_perm((unsigned int)pk23, (unsigned int)pk01, 0x06040200u) ^ 0x80808080u;
}

// ---- scales: 0..63 W-max | 64..127 U-max | 128 b-max+quant+cnt reset |
// ---- 129..192 x -> xh/xl bf16 split ----
__global__ __launch_bounds__(256) void scales_kernel(const float* __restrict__ W,
                                                     const float* __restrict__ U,
                                                     const float* __restrict__ b,
                                                     const float* __restrict__ x,
                                                     float* __restrict__ ws) {
    __shared__ float ls[4];
    __shared__ float sbS;
    const int t = threadIdx.x, wave = t >> 6, lane = t & 63;
    const int bid = blockIdx.x;
    if (bid < 128) {
        const float4* src; int n4, rb;
        if (bid < 64) { src = (const float4*)W; n4 = N_DIM * N_DIM / 4; rb = bid; }
        else          { src = (const float4*)U; n4 = N_DIM * D_DIM / 4; rb = bid - 64; }
        float mv = 0.0f;
        for (int i = rb * 256 + t; i < n4; i += 64 * 256) {
            float4 v = src[i];
            mv = fmaxf(mv, fmaxf(fmaxf(fabsf(v.x), fabsf(v.y)), fmaxf(fabsf(v.z), fabsf(v.w))));
        }
#pragma unroll
        for (int s = 1; s < 64; s <<= 1) mv = fmaxf(mv, __shfl_xor(mv, s));
        if (lane == 0) ls[wave] = mv;
        __syncthreads();
        if (t == 0) ws[bid] = fmaxf(fmaxf(ls[0], ls[1]), fmaxf(ls[2], ls[3]));
    } else if (bid == 128) {
        // b: block-local max + quantize bq = rint(b/sb)*sb; reset counters
        if (t == 0) { ((int*)ws)[WSF_CNTW] = 0; ((int*)ws)[WSF_CNTU] = 0; }
        float4 v = {0.0f, 0.0f, 0.0f, 0.0f};
        if (t < N_DIM / 4) v = ((const float4*)b)[t];
        float mv = fmaxf(fmaxf(fabsf(v.x), fabsf(v.y)), fmaxf(fabsf(v.z), fabsf(v.w)));
#pragma unroll
        for (int s = 1; s < 64; s <<= 1) mv = fmaxf(mv, __shfl_xor(mv, s));
        if (lane == 0) ls[wave] = mv;
        __syncthreads();
        if (t == 0) {
            float m = fmaxf(fmaxf(ls[0], ls[1]), fmaxf(ls[2], ls[3]));
            float sb = m * (1.0f / QMAX);
            ws[WSF_SB] = sb;
            sbS = sb;
        }
        __syncthreads();
        if (t < N_DIM / 4) {
            const float sb = sbS;
            float4 o;
            o.x = rintf(v.x / sb) * sb;
            o.y = rintf(v.y / sb) * sb;
            o.z = rintf(v.z / sb) * sb;
            o.w = rintf(v.w / sb) * sb;
            ((float4*)(ws + WSF_BQ))[t] = o;
        }
    } else {
        // xsplit: 64 blocks over 128x196 float4s
        __bf16* xh = (__bf16*)(ws + WSF_XH);
        __bf16* xl = (__bf16*)(ws + WSF_XL);
        const int xb = bid - 129;
        for (int i = xb * 256 + t; i < 128 * 196; i += 64 * 256) {
            int r = i / 196, kf = i - r * 196;
            float4 v = *(const float4*)&x[r * D_DIM + (kf << 2)];
            union { __bf16 e[4]; ushort4 u; } hh, ll;
            __bf16 h0 = (__bf16)v.x, h1 = (__bf16)v.y, h2 = (__bf16)v.z, h3 = (__bf16)v.w;
            hh.e[0] = h0; hh.e[1] = h1; hh.e[2] = h2; hh.e[3] = h3;
            ll.e[0] = (__bf16)(v.x - (float)h0);
            ll.e[1] = (__bf16)(v.y - (float)h1);
            ll.e[2] = (__bf16)(v.z - (float)h2);
            ll.e[3] = (__bf16)(v.w - (float)h3);
            *(ushort4*)&xh[r * XPITCH + (kf << 2)] = hh.u;
            *(ushort4*)&xl[r * XPITCH + (kf << 2)] = ll.u;
        }
        if (xb == 0) {
            // zero pad cols [784,800) for all 128 rows (8 bf16 per thread)
            int r = t >> 1, c = D_DIM + (t & 1) * 8;
            ushort4 z = {0, 0, 0, 0};
            *(ushort4*)&xh[r * XPITCH + c] = z; *(ushort4*)&xh[r * XPITCH + c + 4] = z;
            *(ushort4*)&xl[r * XPITCH + c] = z; *(ushort4*)&xl[r * XPITCH + c + 4] = z;
        }
    }
}

// ------- fused: 0..63 W-quant | 64..79 UxT (32-row slices) | 80..87 solve -------
__global__ __launch_bounds__(1024, 1) void fused_kernel(const float* __restrict__ W,
                                                        const float* __restrict__ U,
                                                        float* __restrict__ ws,
                                                        const float* __restrict__ Wc,
                                                        const float* __restrict__ bc,
                                                        float* __restrict__ out) {
    __shared__ __align__(16) char LDS[54272]; // solve: zh|zl|WcS (red aliases zh) / UxT: quS
    const int t = threadIdx.x;
    const int wave = t >> 6, lane = t & 63;
    const int bid = blockIdx.x;
    signed char* Qp8 = (signed char*)(ws + WSF_QP8);
    int* cntW = (int*)ws + WSF_CNTW;
    int* cntU = (int*)ws + WSF_CNTU;

    if (bid < 64) {
        // ---- W quant (8 rows per block), wide & coalesced ----
        const float s = pscale64(ws + WSF_PW);
        const float inv = 1.0f / s;
        int idx = bid * 1024 + t;                  // float4 index into W
        float4 w = ((const float4*)W)[idx];
        int k = (idx << 2) & (N_DIM - 1);
        int r = (idx << 2) >> 9;
        char4 c;
        c.x = (signed char)(int)rintf(w.x * inv);
        c.y = (signed char)(int)rintf(w.y * inv);
        c.z = (signed char)(int)rintf(w.z * inv);
        c.w = (signed char)(int)rintf(w.w * inv);
        int kc = k >> 6, q = (k >> 4) & 3, jj = k & 15;
        *(char4*)&Qp8[((kc << 9) + r) * 64 + q * 16 + jj] = c;
        __syncthreads();   // drain stores (vmcnt) before publish
        if (t == 0) __hip_atomic_fetch_add(cntW, 1, __ATOMIC_RELEASE, __HIP_MEMORY_SCOPE_AGENT);
        return;
    }
    if (bid < 80) {
        // ---- UxT rows [i0,i0+32): quantize U-slice once; wave=(rowhalf,cg),
        // ---- all 16 waves active; per-output kc order 0..24 (bit-exact) ----
        __bf16 (*quS)[QUPITCH] = (__bf16 (*)[QUPITCH])LDS;   // 32*808*2 = 51712 B
        const float sU = pscale64(ws + WSF_PU);
        const float invU = 1.0f / sU;
        const int i0 = (bid - 64) * 32;
        for (int i = t; i < 32 * 196; i += 1024) {
            int r = i / 196, kf = i - r * 196;
            float4 v = *(const float4*)&U[(i0 + r) * D_DIM + (kf << 2)];
            union { __bf16 e[4]; ushort4 u; } q;
            q.e[0] = (__bf16)rintf(v.x * invU);
            q.e[1] = (__bf16)rintf(v.y * invU);
            q.e[2] = (__bf16)rintf(v.z * invU);
            q.e[3] = (__bf16)rintf(v.w * invU);
            *(ushort4*)&quS[r][kf << 2] = q.u;
        }
        if (t < 512) { int r = t >> 4, k = D_DIM + (t & 15); quS[r][k] = (__bf16)0.0f; }
        __syncthreads();
        {
            const int m = lane & 15, quad = lane >> 4;
            const int rh = wave >> 3;          // 0/1: which 16-row half
            const int cg = wave & 7;           // batch-col group
            const __bf16* xh = (const __bf16*)(ws + WSF_XH);
            const __bf16* xl = (const __bf16*)(ws + WSF_XL);
            const float* bq = ws + WSF_BQ;
            float* UxT = ws + WSF_UXT;
            const int row0 = i0 + rh * 16 + (quad << 2);
            const f32x4 bqv = *(const f32x4*)&bq[row0];
            const __bf16* xhr = &xh[(cg * 16 + m) * XPITCH];
            const __bf16* xlr = &xl[(cg * 16 + m) * XPITCH];
            f32x4 acc = {};
#pragma unroll 5
            for (int kc = 0; kc < 25; ++kc) {
                bf16x8 au = *(const bf16x8*)&quS[rh * 16 + m][kc * 32 + (quad << 3)];
                bf16x8 bh = *(const bf16x8*)&xhr[kc * 32 + (quad << 3)];
                bf16x8 bl = *(const bf16x8*)&xlr[kc * 32 + (quad << 3)];
                acc = __builtin_amdgcn_mfma_f32_16x16x32_bf16(au, bh, acc, 0, 0, 0);
                acc = __builtin_amdgcn_mfma_f32_16x16x32_bf16(au, bl, acc, 0, 0, 0);
            }
            f32x4 o;
#pragma unroll
            for (int r = 0; r < 4; ++r) o[r] = sU * acc[r] + bqv[r];
            *(f32x4*)&UxT[(cg * 16 + m) * N_DIM + row0] = o;
        }
        __syncthreads();   // drain stores before publish
        if (t == 0) __hip_atomic_fetch_add(cntU, 1, __ATOMIC_RELEASE, __HIP_MEMORY_SCOPE_AGENT);
        return;
    }

    // ---------------- solve (bids 80..87) ----------------
    signed char (*zh)[16][ZPITCH] = (signed char (*)[16][ZPITCH])(LDS);            // 16896 B
    signed char (*zl)[16][ZPITCH] = (signed char (*)[16][ZPITCH])(LDS + 16896);    // 16896 B
    float* WcS                    = (float*)(LDS + 33792);                         // 20480 B
    float (*red)[16][C_DIM]       = (float (*)[16][C_DIM])(LDS);                   // aliases zh (post-loop)
    const float* UxT = ws + WSF_UXT;
    const int m = lane & 15;      // batch col within block tile
    const int quad = lane >> 4;   // D-row group
    const int c0 = (bid - 80) * 16;
    const float sW = pscale64(ws + WSF_PW);
    const float c1 = sW * (1.0f / 2048.0f);
    const float hc_hi = c1 * 128.0f;     // original-units constants
    const float g_hi = sW * 128.0f;      // = hc_hi * 2048 (exact)
    const float g_lo = sW * 0.5f;        // = hc_lo * 2048 (exact)
    const int rowbase = wave * 32;

    // wait for W-quant producers only (UxT still running)
    if (t == 0) {
        while (__hip_atomic_load(cntW, __ATOMIC_RELAXED, __HIP_MEMORY_SCOPE_AGENT) < N_PW)
            __builtin_amdgcn_s_sleep(8);
    }
    __syncthreads();
    (void)__hip_atomic_load(cntW, __ATOMIC_ACQUIRE, __HIP_MEMORY_SCOPE_AGENT);

    // kc-stagger: wave w consumes kc in order (j+w)&7. A-frags loaded
    // pre-rotated so all register indices stay STATIC (rule #20); i32
    // accumulation is commutative -> bit-exact.
    const int kst = wave & 7;
    int kidx[8];
#pragma unroll
    for (int j = 0; j < 8; ++j) kidx[j] = (j + kst) & 7;

    i32x4 A[MT][8];    // A[ti][j] holds fragment for kc = kidx[j]
#pragma unroll
    for (int ti = 0; ti < MT; ++ti)
#pragma unroll
        for (int j = 0; j < 8; ++j)
            A[ti][j] = *(const i32x4*)&Qp8[((kidx[j] << 9) + rowbase + ti * 16 + m) * 64 + (quad << 4)];

    // rowsum(Q) per row via ones-vector i8 MFMA (int, order-independent)
    const i32x4 onesb = {0x01010101, 0x01010101, 0x01010101, 0x01010101};
    i32x4 rs[MT];
#pragma unroll
    for (int ti = 0; ti < MT; ++ti) {
        i32x4 a = {};
#pragma unroll
        for (int j = 0; j < 8; ++j)
            a = __builtin_amdgcn_mfma_i32_16x16x64_i8(A[ti][j], onesb, a, 0, 0, 0);
        rs[ti] = a;
    }

    // stage Wc into LDS (overlaps UxT tail; logits will read broadcast)
    for (int i = t; i < C_DIM * N_DIM; i += 1024) WcS[i] = Wc[i];

    // wait for UxT producers
    if (t == 0) {
        while (__hip_atomic_load(cntU, __ATOMIC_RELAXED, __HIP_MEMORY_SCOPE_AGENT) < N_PU)
            __builtin_amdgcn_s_sleep(8);
    }
    __syncthreads();
    (void)__hip_atomic_load(cntU, __ATOMIC_ACQUIRE, __HIP_MEMORY_SCOPE_AGENT);

    // prologue. Scaled units: Z = 2048*z (exact 2^11), UX2 = 2048*uxh.
    float Z[MT][4];
    float UX2[MT][4];
#pragma unroll
    for (int ti = 0; ti < MT; ++ti) {
        const int row0 = rowbase + ti * 16 + (quad << 2);
        const f32x4 v4 = *(const f32x4*)&UxT[(c0 + m) * N_DIM + row0];
        int vq[4];
#pragma unroll
        for (int r = 0; r < 4; ++r) {
            const float v = v4[r];
            const float uxh = 0.5f * (v + hc_hi * (float)rs[ti][r]);
            UX2[ti][r] = uxh * 2048.0f;
            const float z1 = fmaxf(0.5f * v, 0.0f);
            const float Z1 = z1 * 2048.0f;
            Z[ti][r] = Z1;
            vq[r] = (int)rintf(Z1);
        }
        unsigned int h, l;
        pack_hl(vq, h, l);
        *(unsigned int*)&zh[0][m][row0] = h;
        *(unsigned int*)&zl[0][m][row0] = l;
    }

#pragma unroll
    for (int ti = 0; ti < MT; ++ti)
#pragma unroll
        for (int j = 0; j < 8; ++j)
            asm volatile("" : "+v"(A[ti][j]));
    __syncthreads();

    int cur = 0;
    for (int it = 1; it < N_ITERS; ++it) {
        const bool lo = (it >= HILO_START);
        const bool wlo = (it >= HILO_START - 1);
        i32x4 acch[MT] = {};
        i32x4 accl[MT] = {};
        if (lo) {
#pragma unroll
            for (int j = 0; j < 8; ++j) {
                const int ka = (kidx[j] << 6) + (quad << 4);
                i32x4 bh = *(const i32x4*)&zh[cur][m][ka];
                i32x4 bl = *(const i32x4*)&zl[cur][m][ka];
#pragma unroll
                for (int ti = 0; ti < MT; ++ti) {
                    acch[ti] = __builtin_amdgcn_mfma_i32_16x16x64_i8(A[ti][j], bh, acch[ti], 0, 0, 0);
                    accl[ti] = __builtin_amdgcn_mfma_i32_16x16x64_i8(A[ti][j], bl, accl[ti], 0, 0, 0);
                }
            }
        } else {
#pragma unroll
            for (int j = 0; j < 8; ++j) {
                const int ka = (kidx[j] << 6) + (quad << 4);
                i32x4 bh = *(const i32x4*)&zh[cur][m][ka];
#pragma unroll
                for (int ti = 0; ti < MT; ++ti)
                    acch[ti] = __builtin_amdgcn_mfma_i32_16x16x64_i8(A[ti][j], bh, acch[ti], 0, 0, 0);
            }
        }
        const int nxt = cur ^ 1;
#pragma unroll
        for (int ti = 0; ti < MT; ++ti) {
            const int row0 = rowbase + ti * 16 + (quad << 2);
            int vq[4];
#pragma unroll
            for (int r = 0; r < 4; ++r) {
                float base = fmaf(0.5f, Z[ti][r], UX2[ti][r]);
                float u = lo ? fmaf(g_hi, (float)acch[ti][r], fmaf(g_lo, (float)accl[ti][r], base))
                             : fmaf(g_hi, (float)acch[ti][r], base);
                float Zn = fmaxf(u, 0.0f);
                Z[ti][r] = Zn;
                vq[r] = (int)rintf(Zn);
            }
            unsigned int h, l;
            pack_hl(vq, h, l);
            *(unsigned int*)&zh[nxt][m][row0] = h;
            if (wlo) *(unsigned int*)&zl[nxt][m][row0] = l;
        }
        __syncthreads();
        cur = nxt;
    }

    // ---- fused logits from register z (Wc from LDS; red aliases dead zh) ----
    {
        float p[C_DIM];
#pragma unroll
        for (int cl = 0; cl < C_DIM; ++cl) p[cl] = 0.0f;
#pragma unroll
        for (int ti = 0; ti < MT; ++ti) {
            const int row0 = rowbase + ti * 16 + (quad << 2);
#pragma unroll
            for (int r = 0; r < 4; ++r) {
                float zv = Z[ti][r] * (1.0f / 2048.0f);
#pragma unroll
                for (int cl = 0; cl < C_DIM; ++cl)
                    p[cl] += zv * WcS[cl * N_DIM + row0 + r];
            }
        }
#pragma unroll
        for (int cl = 0; cl < C_DIM; ++cl) {
            p[cl] += __shfl_xor(p[cl], 16);
            p[cl] += __shfl_xor(p[cl], 32);
        }
        if (lane < 16) {
#pragma unroll
            for (int cl = 0; cl < C_DIM; ++cl) red[wave][lane][cl] = p[cl];
        }
        __syncthreads();
        for (int s = 8; s > 0; s >>= 1) {
            if (wave < s && lane < 16) {
#pragma unroll
                for (int cl = 0; cl < C_DIM; ++cl)
                    red[wave][lane][cl] += red[wave + s][lane][cl];
            }
            __syncthreads();
        }
        if (t < 16 * C_DIM) {
            int col = t & 15;
            int cl  = t >> 4;
            out[(c0 + col) * C_DIM + cl] = red[0][col][cl] + bc[cl];
        }
    }
}

extern "C" void kernel_launch(void* const* d_in, const int* in_sizes, int n_in,
                              void* d_out, int out_size, void* d_ws, size_t ws_size,
                              hipStream_t stream) {
    const float* W  = (const float*)d_in[0];
    const float* U  = (const float*)d_in[1];
    const float* b  = (const float*)d_in[2];
    const float* x  = (const float*)d_in[3];
    const float* Wc = (const float*)d_in[4];
    const float* bc = (const float*)d_in[5];
    float* out = (float*)d_out;
    float* ws = (float*)d_ws;

    scales_kernel<<<193, 256, 0, stream>>>(W, U, b, x, ws);
    fused_kernel<<<88, 1024, 0, stream>>>(W, U, ws, Wc, bc, out);
}

// Round 8
// 138.398 us; speedup vs baseline: 1.0225x; 1.0225x over previous
//
#include <hip/hip_runtime.h>
#include <hip/hip_bf16.h>

// QuantisedMonDEQ: n=512, d=784, B=128, C=10. All inputs/outputs float32.
// z_{t+1} = relu(0.5 z + 0.5 (Wq z + Ux)), 40 iters; logits = z*^T Wc^T + bc.
//
// INT8 formulation: Wq = sW*Q, Q = rint(W/sW) exact int8. z held as Q4.11
// fixed point v (int16), split v = 256*zh + (zlm+128), zh,zlm int8.
//   Q.v = 256*(Q.zh) + Q.zlm + 128*rowsum(Q)   (rowsum folded into Ux).
// Iters 1..27: hi-plane only; iters 28..39 both planes. Z (=2048*z, exact
// 2^11 scaling) + Ux fold live in registers; LDS carries only the int8
// B-plane transpose. Rowsum via ones-vector i8 MFMA.
//
// Round-8 (post-mortem r7): kc-stagger left SQ_LDS_BANK_CONFLICT bit-identical
// (262,528) -> conflicts are the STRUCTURAL wave64-b128 depth-8 floor, not
// removable; reverted stagger (restores compile-time ds offsets). Attack the
// VALU epilogue (~48% of solve cycles) with exact-arithmetic cuts:
//  * v_pk_fma_f32 (gfx950 packed FP32 -- how the 157TF spec is reached;
//    compiler never auto-packs): halves the 3-deep fma chain. Same values,
//    same fma order (lo-fma inner, hi-fma outer).
//  * magic-add RNE pack: bits(Zn + 2^23) holds rint(Zn) in bytes 0-1
//    (Zn in [0, 32768) -- z*2048 ~< 22K); two v_perm merges replace
//    rndne + cvt_i32 + cvt_pk_i16. Identical to rintf for in-range values.
//  * Wc->LDS stage moved before the cntW poll (input-only dependency).
// Dispatch: scales(193) -> fused(88): 0..63 W-quant | 64..79 UxT | 80..87 solve.

#define N_DIM 512
#define D_DIM 784
#define B_DIM 128
#define C_DIM 10
#define QMAX 127.0f
#define N_ITERS 40
#define HILO_START 28
#define ZPITCH 528     // bytes per column plane row; 16B-aligned
#define MT 2           // 16-row M-tiles per wave (16 waves x 32 rows = 512)
#define XPITCH 800     // bf16 elems per x row in ws (784 data + 16 zero pad)
#define QUPITCH 808    // bf16 elems per U row in LDS (pad spreads banks)
#define MAGIC 8388608.0f   // 2^23: f32 RNE integerize for 0 <= v < 2^23

typedef int    i32x4  __attribute__((ext_vector_type(4)));
typedef float  f32x4  __attribute__((ext_vector_type(4)));
typedef float  f32x2  __attribute__((ext_vector_type(2)));
typedef __bf16 bf16x8 __attribute__((ext_vector_type(8)));

// ws float offsets (scalars/partials fully rewritten each replay)
#define WSF_PW   0                   // 64 W partial maxes
#define WSF_PU   64                  // 64 U partial maxes
#define WSF_SB   128                 // sb scalar
#define WSF_CNTW 160                 // int: W-quant done counter (own line)
#define WSF_CNTU 224                 // int: UxT done counter (own line)
#define WSF_BQ   288                 // bq[512] fp32
#define WSF_XH   800                 // xh bf16 [128][XPITCH] = 51200 floats
#define WSF_XL   (WSF_XH + 51200)    // xl bf16 [128][XPITCH]
#define WSF_QP8  (WSF_XL + 51200)    // Qp8 int8 512x512 = 65536 floats
#define WSF_UXT  (WSF_QP8 + 65536)   // UxT fp32 [128][512]

#define N_PW 64
#define N_PU 16

__device__ __forceinline__ float pscale64(const float* __restrict__ p) {
    float m = 0.0f;
#pragma unroll 16
    for (int i = 0; i < 64; ++i) m = fmaxf(m, p[i]);
    return m * (1.0f / QMAX);
}

// packed fp32 fma: d[i] = a[i]*b[i] + c[i], i=0,1 (bit-identical to scalar fma)
__device__ __forceinline__ f32x2 pk_fma(f32x2 a, f32x2 b, f32x2 c) {
    f32x2 d;
    asm("v_pk_fma_f32 %0, %1, %2, %3" : "=v"(d) : "v"(a), "v"(b), "v"(c));
    return d;
}

// z0..z3 (>=0, < 32768 after RNE): h = hi bytes of rint(z), l = lo bytes ^ 0x80.
__device__ __forceinline__ void pack_hl_f(float z0, float z1, float z2, float z3,
                                          unsigned int& h, unsigned int& l) {
    unsigned int f0 = __float_as_uint(z0 + MAGIC);
    unsigned int f1 = __float_as_uint(z1 + MAGIC);
    unsigned int f2 = __float_as_uint(z2 + MAGIC);
    unsigned int f3 = __float_as_uint(z3 + MAGIC);
    unsigned int m01 = __builtin_amdgcn_perm(f1, f0, 0x05040100u); // [b0f0,b1f0,b0f1,b1f1]
    unsigned int m23 = __builtin_amdgcn_perm(f3, f2, 0x05040100u);
    h = __builtin_amdgcn_perm(m23, m01, 0x07050301u);
    l = __builtin_amdgcn_perm(m23, m01, 0x06040200u) ^ 0x80808080u;
}

// ---- scales: 0..63 W-max | 64..127 U-max | 128 b-max+quant+cnt reset |
// ---- 129..192 x -> xh/xl bf16 split ----
__global__ __launch_bounds__(256) void scales_kernel(const float* __restrict__ W,
                                                     const float* __restrict__ U,
                                                     const float* __restrict__ b,
                                                     const float* __restrict__ x,
                                                     float* __restrict__ ws) {
    __shared__ float ls[4];
    __shared__ float sbS;
    const int t = threadIdx.x, wave = t >> 6, lane = t & 63;
    const int bid = blockIdx.x;
    if (bid < 128) {
        const float4* src; int n4, rb;
        if (bid < 64) { src = (const float4*)W; n4 = N_DIM * N_DIM / 4; rb = bid; }
        else          { src = (const float4*)U; n4 = N_DIM * D_DIM / 4; rb = bid - 64; }
        float mv = 0.0f;
        for (int i = rb * 256 + t; i < n4; i += 64 * 256) {
            float4 v = src[i];
            mv = fmaxf(mv, fmaxf(fmaxf(fabsf(v.x), fabsf(v.y)), fmaxf(fabsf(v.z), fabsf(v.w))));
        }
#pragma unroll
        for (int s = 1; s < 64; s <<= 1) mv = fmaxf(mv, __shfl_xor(mv, s));
        if (lane == 0) ls[wave] = mv;
        __syncthreads();
        if (t == 0) ws[bid] = fmaxf(fmaxf(ls[0], ls[1]), fmaxf(ls[2], ls[3]));
    } else if (bid == 128) {
        // b: block-local max + quantize bq = rint(b/sb)*sb; reset counters
        if (t == 0) { ((int*)ws)[WSF_CNTW] = 0; ((int*)ws)[WSF_CNTU] = 0; }
        float4 v = {0.0f, 0.0f, 0.0f, 0.0f};
        if (t < N_DIM / 4) v = ((const float4*)b)[t];
        float mv = fmaxf(fmaxf(fabsf(v.x), fabsf(v.y)), fmaxf(fabsf(v.z), fabsf(v.w)));
#pragma unroll
        for (int s = 1; s < 64; s <<= 1) mv = fmaxf(mv, __shfl_xor(mv, s));
        if (lane == 0) ls[wave] = mv;
        __syncthreads();
        if (t == 0) {
            float m = fmaxf(fmaxf(ls[0], ls[1]), fmaxf(ls[2], ls[3]));
            float sb = m * (1.0f / QMAX);
            ws[WSF_SB] = sb;
            sbS = sb;
        }
        __syncthreads();
        if (t < N_DIM / 4) {
            const float sb = sbS;
            float4 o;
            o.x = rintf(v.x / sb) * sb;
            o.y = rintf(v.y / sb) * sb;
            o.z = rintf(v.z / sb) * sb;
            o.w = rintf(v.w / sb) * sb;
            ((float4*)(ws + WSF_BQ))[t] = o;
        }
    } else {
        // xsplit: 64 blocks over 128x196 float4s
        __bf16* xh = (__bf16*)(ws + WSF_XH);
        __bf16* xl = (__bf16*)(ws + WSF_XL);
        const int xb = bid - 129;
        for (int i = xb * 256 + t; i < 128 * 196; i += 64 * 256) {
            int r = i / 196, kf = i - r * 196;
            float4 v = *(const float4*)&x[r * D_DIM + (kf << 2)];
            union { __bf16 e[4]; ushort4 u; } hh, ll;
            __bf16 h0 = (__bf16)v.x, h1 = (__bf16)v.y, h2 = (__bf16)v.z, h3 = (__bf16)v.w;
            hh.e[0] = h0; hh.e[1] = h1; hh.e[2] = h2; hh.e[3] = h3;
            ll.e[0] = (__bf16)(v.x - (float)h0);
            ll.e[1] = (__bf16)(v.y - (float)h1);
            ll.e[2] = (__bf16)(v.z - (float)h2);
            ll.e[3] = (__bf16)(v.w - (float)h3);
            *(ushort4*)&xh[r * XPITCH + (kf << 2)] = hh.u;
            *(ushort4*)&xl[r * XPITCH + (kf << 2)] = ll.u;
        }
        if (xb == 0) {
            // zero pad cols [784,800) for all 128 rows (8 bf16 per thread)
            int r = t >> 1, c = D_DIM + (t & 1) * 8;
            ushort4 z = {0, 0, 0, 0};
            *(ushort4*)&xh[r * XPITCH + c] = z; *(ushort4*)&xh[r * XPITCH + c + 4] = z;
            *(ushort4*)&xl[r * XPITCH + c] = z; *(ushort4*)&xl[r * XPITCH + c + 4] = z;
        }
    }
}

// ------- fused: 0..63 W-quant | 64..79 UxT (32-row slices) | 80..87 solve -------
__global__ __launch_bounds__(1024, 1) void fused_kernel(const float* __restrict__ W,
                                                        const float* __restrict__ U,
                                                        float* __restrict__ ws,
                                                        const float* __restrict__ Wc,
                                                        const float* __restrict__ bc,
                                                        float* __restrict__ out) {
    __shared__ __align__(16) char LDS[54272]; // solve: zh|zl|WcS (red aliases zh) / UxT: quS
    const int t = threadIdx.x;
    const int wave = t >> 6, lane = t & 63;
    const int bid = blockIdx.x;
    signed char* Qp8 = (signed char*)(ws + WSF_QP8);
    int* cntW = (int*)ws + WSF_CNTW;
    int* cntU = (int*)ws + WSF_CNTU;

    if (bid < 64) {
        // ---- W quant (8 rows per block), wide & coalesced ----
        const float s = pscale64(ws + WSF_PW);
        const float inv = 1.0f / s;
        int idx = bid * 1024 + t;                  // float4 index into W
        float4 w = ((const float4*)W)[idx];
        int k = (idx << 2) & (N_DIM - 1);
        int r = (idx << 2) >> 9;
        char4 c;
        c.x = (signed char)(int)rintf(w.x * inv);
        c.y = (signed char)(int)rintf(w.y * inv);
        c.z = (signed char)(int)rintf(w.z * inv);
        c.w = (signed char)(int)rintf(w.w * inv);
        int kc = k >> 6, q = (k >> 4) & 3, jj = k & 15;
        *(char4*)&Qp8[((kc << 9) + r) * 64 + q * 16 + jj] = c;
        __syncthreads();   // drain stores (vmcnt) before publish
        if (t == 0) __hip_atomic_fetch_add(cntW, 1, __ATOMIC_RELEASE, __HIP_MEMORY_SCOPE_AGENT);
        return;
    }
    if (bid < 80) {
        // ---- UxT rows [i0,i0+32): quantize U-slice once; wave=(rowhalf,cg),
        // ---- all 16 waves active; per-output kc order 0..24 (bit-exact) ----
        __bf16 (*quS)[QUPITCH] = (__bf16 (*)[QUPITCH])LDS;   // 32*808*2 = 51712 B
        const float sU = pscale64(ws + WSF_PU);
        const float invU = 1.0f / sU;
        const int i0 = (bid - 64) * 32;
        for (int i = t; i < 32 * 196; i += 1024) {
            int r = i / 196, kf = i - r * 196;
            float4 v = *(const float4*)&U[(i0 + r) * D_DIM + (kf << 2)];
            union { __bf16 e[4]; ushort4 u; } q;
            q.e[0] = (__bf16)rintf(v.x * invU);
            q.e[1] = (__bf16)rintf(v.y * invU);
            q.e[2] = (__bf16)rintf(v.z * invU);
            q.e[3] = (__bf16)rintf(v.w * invU);
            *(ushort4*)&quS[r][kf << 2] = q.u;
        }
        if (t < 512) { int r = t >> 4, k = D_DIM + (t & 15); quS[r][k] = (__bf16)0.0f; }
        __syncthreads();
        {
            const int m = lane & 15, quad = lane >> 4;
            const int rh = wave >> 3;          // 0/1: which 16-row half
            const int cg = wave & 7;           // batch-col group
            const __bf16* xh = (const __bf16*)(ws + WSF_XH);
            const __bf16* xl = (const __bf16*)(ws + WSF_XL);
            const float* bq = ws + WSF_BQ;
            float* UxT = ws + WSF_UXT;
            const int row0 = i0 + rh * 16 + (quad << 2);
            const f32x4 bqv = *(const f32x4*)&bq[row0];
            const __bf16* xhr = &xh[(cg * 16 + m) * XPITCH];
            const __bf16* xlr = &xl[(cg * 16 + m) * XPITCH];
            f32x4 acc = {};
#pragma unroll 5
            for (int kc = 0; kc < 25; ++kc) {
                bf16x8 au = *(const bf16x8*)&quS[rh * 16 + m][kc * 32 + (quad << 3)];
                bf16x8 bh = *(const bf16x8*)&xhr[kc * 32 + (quad << 3)];
                bf16x8 bl = *(const bf16x8*)&xlr[kc * 32 + (quad << 3)];
                acc = __builtin_amdgcn_mfma_f32_16x16x32_bf16(au, bh, acc, 0, 0, 0);
                acc = __builtin_amdgcn_mfma_f32_16x16x32_bf16(au, bl, acc, 0, 0, 0);
            }
            f32x4 o;
#pragma unroll
            for (int r = 0; r < 4; ++r) o[r] = sU * acc[r] + bqv[r];
            *(f32x4*)&UxT[(cg * 16 + m) * N_DIM + row0] = o;
        }
        __syncthreads();   // drain stores before publish
        if (t == 0) __hip_atomic_fetch_add(cntU, 1, __ATOMIC_RELEASE, __HIP_MEMORY_SCOPE_AGENT);
        return;
    }

    // ---------------- solve (bids 80..87) ----------------
    signed char (*zh)[16][ZPITCH] = (signed char (*)[16][ZPITCH])(LDS);            // 16896 B
    signed char (*zl)[16][ZPITCH] = (signed char (*)[16][ZPITCH])(LDS + 16896);    // 16896 B
    float* WcS                    = (float*)(LDS + 33792);                         // 20480 B
    float (*red)[16][C_DIM]       = (float (*)[16][C_DIM])(LDS);                   // aliases zh (post-loop)
    const float* UxT = ws + WSF_UXT;
    const int m = lane & 15;      // batch col within block tile
    const int quad = lane >> 4;   // D-row group
    const int c0 = (bid - 80) * 16;
    const float sW = pscale64(ws + WSF_PW);
    const float c1 = sW * (1.0f / 2048.0f);
    const float hc_hi = c1 * 128.0f;     // original-units constants
    const float g_hi = sW * 128.0f;      // = hc_hi * 2048 (exact)
    const float g_lo = sW * 0.5f;        // = hc_lo * 2048 (exact)
    const int rowbase = wave * 32;

    // stage Wc into LDS first: input-only dependency, overlaps producer wait
    for (int i = t; i < C_DIM * N_DIM; i += 1024) WcS[i] = Wc[i];

    // wait for W-quant producers only (UxT still running)
    if (t == 0) {
        while (__hip_atomic_load(cntW, __ATOMIC_RELAXED, __HIP_MEMORY_SCOPE_AGENT) < N_PW)
            __builtin_amdgcn_s_sleep(8);
    }
    __syncthreads();
    (void)__hip_atomic_load(cntW, __ATOMIC_ACQUIRE, __HIP_MEMORY_SCOPE_AGENT);

    // register-resident A fragments: 8 kc x 2 M-tiles x 16B (static kc order)
    i32x4 A[MT][8];
#pragma unroll
    for (int ti = 0; ti < MT; ++ti)
#pragma unroll
        for (int kc = 0; kc < 8; ++kc)
            A[ti][kc] = *(const i32x4*)&Qp8[((kc << 9) + rowbase + ti * 16 + m) * 64 + (quad << 4)];

    // rowsum(Q) per row via ones-vector i8 MFMA (int, order-independent)
    const i32x4 onesb = {0x01010101, 0x01010101, 0x01010101, 0x01010101};
    i32x4 rs[MT];
#pragma unroll
    for (int ti = 0; ti < MT; ++ti) {
        i32x4 a = {};
#pragma unroll
        for (int kc = 0; kc < 8; ++kc)
            a = __builtin_amdgcn_mfma_i32_16x16x64_i8(A[ti][kc], onesb, a, 0, 0, 0);
        rs[ti] = a;
    }

    // wait for UxT producers
    if (t == 0) {
        while (__hip_atomic_load(cntU, __ATOMIC_RELAXED, __HIP_MEMORY_SCOPE_AGENT) < N_PU)
            __builtin_amdgcn_s_sleep(8);
    }
    __syncthreads();
    (void)__hip_atomic_load(cntU, __ATOMIC_ACQUIRE, __HIP_MEMORY_SCOPE_AGENT);

    // prologue. Scaled units: Z = 2048*z (exact 2^11), UX2 = 2048*uxh.
    // State held as f32x2 pairs for packed epilogue math.
    f32x2 Zp[MT][2];
    f32x2 UX2p[MT][2];
#pragma unroll
    for (int ti = 0; ti < MT; ++ti) {
        const int row0 = rowbase + ti * 16 + (quad << 2);
        const f32x4 v4 = *(const f32x4*)&UxT[(c0 + m) * N_DIM + row0];
        float Zs[4];
#pragma unroll
        for (int r = 0; r < 4; ++r) {
            const float v = v4[r];
            const float uxh = 0.5f * (v + hc_hi * (float)rs[ti][r]);
            UX2p[ti][r >> 1][r & 1] = uxh * 2048.0f;
            const float z1 = fmaxf(0.5f * v, 0.0f);
            const float Z1 = z1 * 2048.0f;
            Zp[ti][r >> 1][r & 1] = Z1;
            Zs[r] = Z1;
        }
        unsigned int h, l;
        pack_hl_f(Zs[0], Zs[1], Zs[2], Zs[3], h, l);
        *(unsigned int*)&zh[0][m][row0] = h;
        *(unsigned int*)&zl[0][m][row0] = l;
    }

#pragma unroll
    for (int ti = 0; ti < MT; ++ti)
#pragma unroll
        for (int kc = 0; kc < 8; ++kc)
            asm volatile("" : "+v"(A[ti][kc]));
    __syncthreads();

    const f32x2 half2 = {0.5f, 0.5f};
    const f32x2 ghi2  = {g_hi, g_hi};
    const f32x2 glo2  = {g_lo, g_lo};

    int cur = 0;
    for (int it = 1; it < N_ITERS; ++it) {
        const bool lo = (it >= HILO_START);
        const bool wlo = (it >= HILO_START - 1);
        i32x4 acch[MT] = {};
        i32x4 accl[MT] = {};
        if (lo) {
#pragma unroll
            for (int kc = 0; kc < 8; ++kc) {
                const int ka = (kc << 6) + (quad << 4);
                i32x4 bh = *(const i32x4*)&zh[cur][m][ka];
                i32x4 bl = *(const i32x4*)&zl[cur][m][ka];
#pragma unroll
                for (int ti = 0; ti < MT; ++ti) {
                    acch[ti] = __builtin_amdgcn_mfma_i32_16x16x64_i8(A[ti][kc], bh, acch[ti], 0, 0, 0);
                    accl[ti] = __builtin_amdgcn_mfma_i32_16x16x64_i8(A[ti][kc], bl, accl[ti], 0, 0, 0);
                }
            }
        } else {
#pragma unroll
            for (int kc = 0; kc < 8; ++kc) {
                const int ka = (kc << 6) + (quad << 4);
                i32x4 bh = *(const i32x4*)&zh[cur][m][ka];
#pragma unroll
                for (int ti = 0; ti < MT; ++ti)
                    acch[ti] = __builtin_amdgcn_mfma_i32_16x16x64_i8(A[ti][kc], bh, acch[ti], 0, 0, 0);
            }
        }
        const int nxt = cur ^ 1;
#pragma unroll
        for (int ti = 0; ti < MT; ++ti) {
            const int row0 = rowbase + ti * 16 + (quad << 2);
            float Zs[4];
#pragma unroll
            for (int pr = 0; pr < 2; ++pr) {
                // base = 0.5*Z + UX2 (packed; bit-identical to scalar fmaf)
                f32x2 base = pk_fma(half2, Zp[ti][pr], UX2p[ti][pr]);
                f32x2 inner = base;
                if (lo) {
                    f32x2 alf;
                    alf[0] = (float)accl[ti][2 * pr];
                    alf[1] = (float)accl[ti][2 * pr + 1];
                    inner = pk_fma(glo2, alf, base);      // lo-fma INNER (order preserved)
                }
                f32x2 ahf;
                ahf[0] = (float)acch[ti][2 * pr];
                ahf[1] = (float)acch[ti][2 * pr + 1];
                f32x2 u = pk_fma(ghi2, ahf, inner);       // hi-fma OUTER
                float Zn0 = fmaxf(u[0], 0.0f);
                float Zn1 = fmaxf(u[1], 0.0f);
                Zp[ti][pr][0] = Zn0;
                Zp[ti][pr][1] = Zn1;
                Zs[2 * pr] = Zn0;
                Zs[2 * pr + 1] = Zn1;
            }
            unsigned int h, l;
            pack_hl_f(Zs[0], Zs[1], Zs[2], Zs[3], h, l);
            *(unsigned int*)&zh[nxt][m][row0] = h;
            if (wlo) *(unsigned int*)&zl[nxt][m][row0] = l;
        }
        __syncthreads();
        cur = nxt;
    }

    // ---- fused logits from register z (Wc from LDS; red aliases dead zh) ----
    {
        float p[C_DIM];
#pragma unroll
        for (int cl = 0; cl < C_DIM; ++cl) p[cl] = 0.0f;
#pragma unroll
        for (int ti = 0; ti < MT; ++ti) {
            const int row0 = rowbase + ti * 16 + (quad << 2);
#pragma unroll
            for (int r = 0; r < 4; ++r) {
                float zv = Zp[ti][r >> 1][r & 1] * (1.0f / 2048.0f);
#pragma unroll
                for (int cl = 0; cl < C_DIM; ++cl)
                    p[cl] += zv * WcS[cl * N_DIM + row0 + r];
            }
        }
#pragma unroll
        for (int cl = 0; cl < C_DIM; ++cl) {
            p[cl] += __shfl_xor(p[cl], 16);
            p[cl] += __shfl_xor(p[cl], 32);
        }
        if (lane < 16) {
#pragma unroll
            for (int cl = 0; cl < C_DIM; ++cl) red[wave][lane][cl] = p[cl];
        }
        __syncthreads();
        for (int s = 8; s > 0; s >>= 1) {
            if (wave < s && lane < 16) {
#pragma unroll
                for (int cl = 0; cl < C_DIM; ++cl)
                    red[wave][lane][cl] += red[wave + s][lane][cl];
            }
            __syncthreads();
        }
        if (t < 16 * C_DIM) {
            int col = t & 15;
            int cl  = t >> 4;
            out[(c0 + col) * C_DIM + cl] = red[0][col][cl] + bc[cl];
        }
    }
}

extern "C" void kernel_launch(void* const* d_in, const int* in_sizes, int n_in,
                              void* d_out, int out_size, void* d_ws, size_t ws_size,
                              hipStream_t stream) {
    const float* W  = (const float*)d_in[0];
    const float* U  = (const float*)d_in[1];
    const float* b  = (const float*)d_in[2];
    const float* x  = (const float*)d_in[3];
    const float* Wc = (const float*)d_in[4];
    const float* bc = (const float*)d_in[5];
    float* out = (float*)d_out;
    float* ws = (float*)d_ws;

    scales_kernel<<<193, 256, 0, stream>>>(W, U, b, x, ws);
    fused_kernel<<<88, 1024, 0, stream>>>(W, U, ws, Wc, bc, out);
}